// Round 15
// baseline (109.299 us; speedup 1.0000x reference)
//
#include <hip/hip_runtime.h>

#define THREADS 256

// problem sizes
#define Bsz 2
#define HWp 16384          // 128*128
#define Ntot (Bsz*HWp)     // 32768
#define HID 256
#define Mm 1728
#define FMC 17
#define W_OFF 98304        // 'out' elements precede 'weights' in d_out

// ws layout (in floats)
#define F1_OFF  0
#define F1_SZ   (Bsz*16*HWp)                 // 524288
#define WB2_OFF (F1_SZ + Ntot*FMC)           // bf16 B2 frags: 442368 shorts
#define WB1_OFF (WB2_OFF + (Mm*HID)/2)       // bf16 w1 frags: 8192 shorts

typedef __attribute__((ext_vector_type(8))) short bf16x8;
typedef __attribute__((ext_vector_type(4))) float f32x4;

static __device__ __forceinline__ short f2bf(float x) {
    unsigned u = __builtin_bit_cast(unsigned, x);
    unsigned r = (u + 0x7fff + ((u >> 16) & 1)) >> 16;
    return (short)r;
}
static __device__ __forceinline__ float bf2f(short s) {
    unsigned u = ((unsigned)(unsigned short)s) << 16;
    return __builtin_bit_cast(float, u);
}

// ---- K13: conv1 512 blocks (1 px/thread) + wB2 cvt 432 blocks + wB1 1 block
__global__ __launch_bounds__(THREADS) void k13_conv1_cvt(const float* __restrict__ feat,
                                                         const float* __restrict__ w1,
                                                         const float* __restrict__ b1,
                                                         float* __restrict__ f1,
                                                         const float* __restrict__ w2g,
                                                         short* __restrict__ wB2,
                                                         const float* __restrict__ w1g,
                                                         short* __restrict__ wB1) {
    int tid = threadIdx.x;
    if (blockIdx.x >= 944) {
        for (int idx = tid; idx < 8192; idx += THREADS) {
            int i = idx & 7, l = (idx >> 3) & 63, h = idx >> 9;
            int k = (l >> 4) * 8 + i, hid = h * 16 + (l & 15);
            wB1[idx] = (k < FMC) ? f2bf(w1g[hid * FMC + k]) : (short)0;
        }
        return;
    }
    if (blockIdx.x >= 512) {
        int t4 = ((blockIdx.x - 512) * THREADS + tid) * 4;
        int i = t4 & 7, l = (t4 >> 3) & 63, ct = (t4 >> 9) & 3, s = (t4 >> 11) & 7, mc = t4 >> 14;
        int col = mc * 64 + ct * 16 + (l & 15);
        int k0 = s * 32 + (l >> 4) * 8 + i;
        f32x4 w = *(const f32x4*)(w2g + col * HID + k0);
        short4 o;
        o.x = f2bf(w[0]); o.y = f2bf(w[1]); o.z = f2bf(w[2]); o.w = f2bf(w[3]);
        *(short4*)(wB2 + t4) = o;
        return;
    }
    // conv1: block = (bb, oc, 4 src rows); thread = one source pixel
    __shared__ float sW[4 * 64 * 4];   // [pp][ic][u*2+v] for this block's oc
    int b = blockIdx.x;
    int rg = b & 15, oc = (b >> 4) & 15, bb = b >> 8;
    int c = tid & 63, r = rg * 4 + (tid >> 6);

    #pragma unroll
    for (int q = 0; q < 4; ++q) {
        int e = tid * 4 + q;
        int v = e & 1, u = (e >> 1) & 1, ic = (e >> 2) & 63, pp = (e >> 8) & 3;
        int pi = pp >> 1, pj = pp & 1;
        float s = 0.f;
        for (int ki = 0; ki < 3; ++ki) {
            bool okki = pi ? (u ? (ki == 2) : (ki <= 1)) : (u ? (ki >= 1) : (ki == 0));
            if (!okki) continue;
            for (int kj = 0; kj < 3; ++kj) {
                bool okkj = pj ? (v ? (kj == 2) : (kj <= 1)) : (v ? (kj >= 1) : (kj == 0));
                if (okkj) s += w1[((oc * 64 + ic) * 3 + ki) * 3 + kj];
            }
        }
        sW[(pp * 64 + ic) * 4 + u * 2 + v] = s;
    }
    __syncthreads();

    float bias = b1[oc];
    float a00 = bias, a01 = bias, a10 = bias, a11 = bias;

    float mt = (r > 0) ? 1.f : 0.f, mb2 = (r < 63) ? 1.f : 0.f;
    float ml = (c > 0) ? 1.f : 0.f, mr2 = (c < 63) ? 1.f : 0.f;
    int ro0 = (r > 0) ? -64 : 0, ro2 = (r < 63) ? 64 : 0;
    int co0 = (c > 0) ? -1 : 0, co2 = (c < 63) ? 1 : 0;

    const float* fb = feat + bb * 64 * 4096 + r * 64 + c;
    for (int ic = 0; ic < 64; ++ic) {
        const float* p1 = fb + ic * 4096;
        const float* p0 = p1 + ro0;
        const float* p2 = p1 + ro2;
        float v00 = p0[co0] * (mt * ml), v01 = p0[0] * mt, v02 = p0[co2] * (mt * mr2);
        float v10 = p1[co0] * ml,        v11 = p1[0],      v12 = p1[co2] * mr2;
        float v20 = p2[co0] * (mb2 * ml), v21 = p2[0] * mb2, v22 = p2[co2] * (mb2 * mr2);

        f32x4 w0 = *(const f32x4*)(sW + (0 * 64 + ic) * 4);
        f32x4 w1v = *(const f32x4*)(sW + (1 * 64 + ic) * 4);
        f32x4 w2v = *(const f32x4*)(sW + (2 * 64 + ic) * 4);
        f32x4 w3 = *(const f32x4*)(sW + (3 * 64 + ic) * 4);

        a00 = fmaf(w0[0], v00, a00); a00 = fmaf(w0[1], v01, a00);
        a00 = fmaf(w0[2], v10, a00); a00 = fmaf(w0[3], v11, a00);
        a01 = fmaf(w1v[0], v01, a01); a01 = fmaf(w1v[1], v02, a01);
        a01 = fmaf(w1v[2], v11, a01); a01 = fmaf(w1v[3], v12, a01);
        a10 = fmaf(w2v[0], v10, a10); a10 = fmaf(w2v[1], v11, a10);
        a10 = fmaf(w2v[2], v20, a10); a10 = fmaf(w2v[3], v21, a10);
        a11 = fmaf(w3[0], v11, a11); a11 = fmaf(w3[1], v12, a11);
        a11 = fmaf(w3[2], v21, a11); a11 = fmaf(w3[3], v22, a11);
    }

    float* fo = f1 + (bb * 16 + oc) * HWp + (2 * r) * 128 + 2 * c;
    *reinterpret_cast<float2*>(fo)       = make_float2(fmaxf(a00, 0.f), fmaxf(a01, 0.f));
    *reinterpret_cast<float2*>(fo + 128) = make_float2(fmaxf(a10, 0.f), fmaxf(a11, 0.f));
}

// ---- K4: conv2 + GEMM1(MFMA) + GEMM2(MFMA) + fused einsum, one kernel -----
// Chunk->wave mapping now BLOCKED (wave w owns a contiguous chunk range,
// processed as adjacent pairs) so each wave's store stream advances
// sequentially through memory: same DRAM pages stay hot across instructions
// and chunks (write page locality), and B-reads become 32KB-contiguous.
__global__ __launch_bounds__(THREADS, 2) void k4_fused(const float* __restrict__ f1,
                                                       const float* __restrict__ w2,
                                                       const float* __restrict__ b2,
                                                       const float* __restrict__ pos,
                                                       const short* __restrict__ wB1,
                                                       const float* __restrict__ b1g,
                                                       const short* __restrict__ wB2,
                                                       const float* __restrict__ b2g,
                                                       const float* __restrict__ x0g,
                                                       float* __restrict__ dout) {
    __shared__ short sA[16384];     // 32 KB packed bf16 hdn
    __shared__ int   sOB[64];
    __shared__ float uni[4084];     // 16.3 KB phase-union

    short* sF  = (short*)uni;       // phase1: 3168 shorts  [ic*3+di][jc<66]
    float* sFM = uni + 1584;        // phase1: 2112 floats  [pix][33]
    short* sXT = (short*)uni;       // phase2: 6632 shorts  [jc][q], stride 195
    float* sOut = uni + 3316;       // phase2: 768 floats

    int tid = threadIdx.x;
    int n0 = blockIdx.x * 64;
    int bb = n0 >> 14, tt = n0 & 16383, I = tt >> 7, J0 = tt & 127;
    int i0 = I >> 1, jmin = J0 >> 1;

    // ---- phase 1a: stage f1 neighborhood (bf16) + zero sFM tail ----
    for (int e = tid; e < 3168; e += THREADS) {
        int jc = e % 66, r2 = e / 66;
        int di = r2 % 3, ic = r2 / 3;
        int y = I + di - 1, x = J0 + jc - 1;
        float v = 0.f;
        if ((unsigned)y < 128u && (unsigned)x < 128u)
            v = f1[(bb * 16 + ic) * HWp + y * 128 + x];
        sF[(ic * 3 + di) * 66 + jc] = f2bf(v);
    }
    for (int e = tid; e < 2112; e += THREADS) sFM[e] = 0.f;
    if (tid < 64) {
        int J = J0 + tid;
        int s = ((I & 1) << 1) | (J & 1);
        int p = ((I >> 1) << 6) | (J >> 1);
        sOB[tid] = W_OFF + ((bb * 4 + s) * 4096 + p) * Mm;
    }
    __syncthreads();

    // ---- phase 1b: conv2 -> sFM (thread = (pix, 4 oc)) ----
    {
        int pix = tid & 63, q = tid >> 6;
        float acc[4];
        #pragma unroll
        for (int o = 0; o < 4; ++o) acc[o] = b2[q * 4 + o];
        #pragma unroll 4
        for (int ic = 0; ic < 16; ++ic) {
            float v[9];
            #pragma unroll
            for (int di = 0; di < 3; ++di) {
                const short* row = sF + (ic * 3 + di) * 66 + pix;
                v[di * 3 + 0] = bf2f(row[0]);
                v[di * 3 + 1] = bf2f(row[1]);
                v[di * 3 + 2] = bf2f(row[2]);
            }
            #pragma unroll
            for (int o = 0; o < 4; ++o) {
                const float* w = w2 + ((q * 4 + o) * 16 + ic) * 9;  // wave-uniform
                acc[o] = fmaf(v[0], w[0], acc[o]); acc[o] = fmaf(v[1], w[1], acc[o]);
                acc[o] = fmaf(v[2], w[2], acc[o]); acc[o] = fmaf(v[3], w[3], acc[o]);
                acc[o] = fmaf(v[4], w[4], acc[o]); acc[o] = fmaf(v[5], w[5], acc[o]);
                acc[o] = fmaf(v[6], w[6], acc[o]); acc[o] = fmaf(v[7], w[7], acc[o]);
                acc[o] = fmaf(v[8], w[8], acc[o]);
            }
        }
        #pragma unroll
        for (int o = 0; o < 4; ++o) sFM[pix * 33 + q * 4 + o] = acc[o];
        if (q == 0) sFM[pix * 33 + 16] = pos[(I * 128 + J0 + pix) * 3];
    }
    __syncthreads();

    int wv = tid >> 6, l = tid & 63, lm = l & 15, lg = l >> 4;

    // ---- phase 1c: read fm row fragment for GEMM1 ----
    int row = wv * 16 + lm;
    bf16x8 af1;
    #pragma unroll
    for (int i = 0; i < 8; ++i) af1[i] = f2bf(sFM[row * 33 + lg * 8 + i]);
    __syncthreads();   // all sFM/sF reads done; uni is now free

    // ---- phase 1d: GEMM1 MFMA -> sA (packed), and stage sXT ----
    {
        const short* wb = wB1 + l * 8;
        int pbase = ((lg >> 1) * 64 + row) * 8 + (lg & 1) * 4;
        #pragma unroll 4
        for (int h = 0; h < 16; ++h) {
            bf16x8 bfr = *(const bf16x8*)(wb + h * 512);
            f32x4 bias = *(const f32x4*)(b1g + h * 16 + lg * 4);
            f32x4 acc = __builtin_amdgcn_mfma_f32_16x16x32_bf16(bfr, af1, bias, 0, 0, 0);
            unsigned c0 = (unsigned short)f2bf(fmaxf(acc[0], 0.f));
            unsigned c1 = (unsigned short)f2bf(fmaxf(acc[1], 0.f));
            unsigned c2 = (unsigned short)f2bf(fmaxf(acc[2], 0.f));
            unsigned c3 = (unsigned short)f2bf(fmaxf(acc[3], 0.f));
            uint2 uv; uv.x = c0 | (c1 << 16); uv.y = c2 | (c3 << 16);
            *(uint2*)(sA + pbase + h * 1024) = uv;
        }
    }
    {
        const float* x0b = x0g + bb * 64 * 4096;
        for (int e = tid; e < 6528; e += THREADS) {
            int ch = e / 102, r2 = e - ch * 102;
            int ki = r2 / 34, jc = r2 - ki * 34;
            int y = i0 + ki - 1, x = jmin + jc - 1;
            float v = 0.f;
            if ((unsigned)y < 64u && (unsigned)x < 64u) v = x0b[(ch * 64 + y) * 64 + x];
            sXT[jc * 195 + ch * 3 + ki] = f2bf(v);
        }
    }
    __syncthreads();

    // ---- phase 2: GEMM2 + weights store + fused einsum (blocked ranges) ----
    int lg3 = lg % 3, lg4 = lg * 4;
    int pixbase[4], jl195[4];
    #pragma unroll
    for (int rt = 0; rt < 4; ++rt) {
        pixbase[rt] = sOB[rt * 16 + lm];
        jl195[rt] = (rt * 8 + (lm >> 1)) * 195;
    }

    const short* aptr = sA + lg * 512 + lm * 8;

    float racc[4][3];
    #pragma unroll
    for (int rt = 0; rt < 4; ++rt) {
        racc[rt][0] = 0.f; racc[rt][1] = 0.f; racc[rt][2] = 0.f;
    }

#define INIT_ACC(ACC, M0)                                                      \
    _Pragma("unroll")                                                          \
    for (int ct = 0; ct < 4; ++ct) {                                           \
        f32x4 bias4 = *(const f32x4*)(b2g + (M0) + ct * 16 + lg4);             \
        _Pragma("unroll")                                                      \
        for (int rt = 0; rt < 4; ++rt) ACC[rt][ct] = bias4;                    \
    }

#define STORE_ACCUM(ACC, MC, M0)                                               \
    _Pragma("unroll")                                                          \
    for (int rt = 0; rt < 4; ++rt)                                             \
        _Pragma("unroll")                                                      \
        for (int ct = 0; ct < 4; ++ct)                                         \
            *(f32x4*)(dout + pixbase[rt] + (M0) + ct * 16 + lg4) = ACC[rt][ct];\
    {                                                                          \
        int qb = (MC) % 3;                                                     \
        switch (qb) {                                                          \
            case 0: ACCUM(ACC, 0, M0); break;                                  \
            case 1: ACCUM(ACC, 1, M0); break;                                  \
            default: ACCUM(ACC, 2, M0); break;                                 \
        }                                                                      \
    }

#define ACCUM(ACC, QB, M0)                                                     \
        _Pragma("unroll")                                                      \
        for (int ct = 0; ct < 4; ++ct) {                                       \
            int t = (M0) + ct * 16 + lg4;                                      \
            int K0 = (t * 21846) >> 16;                                        \
            int rem3 = t - 3 * K0;                                             \
            int Q2 = (K0 * 21846) >> 16;                                       \
            int kja = K0 - 3 * Q2;                                             \
            int kqa = kja * 195 + Q2;                                          \
            int kqb = (kja == 2) ? (Q2 + 1) : (kqa + 195);                     \
            _Pragma("unroll")                                                  \
            for (int rt = 0; rt < 4; ++rt) {                                   \
                float xa = bf2f(sXT[jl195[rt] + kqa]);                         \
                float xb = bf2f(sXT[jl195[rt] + kqb]);                         \
                float x1 = (rem3 == 2) ? xb : xa;                              \
                float x2 = (rem3 >= 1) ? xb : xa;                              \
                racc[rt][(QB + ct) % 3] =                                      \
                    fmaf(ACC[rt][ct][0], xa, racc[rt][(QB + ct) % 3]);         \
                racc[rt][(QB + ct + 1) % 3] =                                  \
                    fmaf(ACC[rt][ct][1], x1, racc[rt][(QB + ct + 1) % 3]);     \
                racc[rt][(QB + ct + 2) % 3] =                                  \
                    fmaf(ACC[rt][ct][2], x2, racc[rt][(QB + ct + 2) % 3]);     \
                racc[rt][(QB + ct) % 3] =                                      \
                    fmaf(ACC[rt][ct][3], xb, racc[rt][(QB + ct) % 3]);         \
            }                                                                  \
        }

    // blocked contiguous ranges: {7,7,7,6} chunks; adjacent pairs (mc, mc+1)
    int lo = (wv < 3) ? wv * 7 : 21;
    int hi = (wv < 3) ? (lo + 7) : 27;
    int mc = lo;
    while (mc + 1 < hi) {
        int m0A = mc * 64, m0B = m0A + 64;
        f32x4 accA[4][4], accB[4][4];
        INIT_ACC(accA, m0A)
        INIT_ACC(accB, m0B)
        const short* bbA = wB2 + (size_t)mc * 16384 + l * 8;
        const short* bbB = bbA + 16384;
        #pragma unroll 2
        for (int s = 0; s < 8; ++s) {
            bf16x8 af[4], bfA[4], bfB[4];
            #pragma unroll
            for (int rt = 0; rt < 4; ++rt)
                af[rt] = *(const bf16x8*)(aptr + s * 2048 + rt * 128);
            #pragma unroll
            for (int ct = 0; ct < 4; ++ct) {
                bfA[ct] = *(const bf16x8*)(bbA + (s * 4 + ct) * 512);
                bfB[ct] = *(const bf16x8*)(bbB + (s * 4 + ct) * 512);
            }
            #pragma unroll
            for (int rt = 0; rt < 4; ++rt)
                #pragma unroll
                for (int ct = 0; ct < 4; ++ct) {
                    accA[rt][ct] = __builtin_amdgcn_mfma_f32_16x16x32_bf16(
                        bfA[ct], af[rt], accA[rt][ct], 0, 0, 0);
                    accB[rt][ct] = __builtin_amdgcn_mfma_f32_16x16x32_bf16(
                        bfB[ct], af[rt], accB[rt][ct], 0, 0, 0);
                }
        }
        STORE_ACCUM(accA, mc, m0A)
        STORE_ACCUM(accB, (mc + 1), m0B)
        mc += 2;
    }
    if (mc < hi) {
        int m0 = mc * 64;
        f32x4 accA[4][4];
        INIT_ACC(accA, m0)
        const short* bbA = wB2 + (size_t)mc * 16384 + l * 8;
        #pragma unroll 2
        for (int s = 0; s < 8; ++s) {
            bf16x8 af[4], bfA[4];
            #pragma unroll
            for (int rt = 0; rt < 4; ++rt)
                af[rt] = *(const bf16x8*)(aptr + s * 2048 + rt * 128);
            #pragma unroll
            for (int ct = 0; ct < 4; ++ct)
                bfA[ct] = *(const bf16x8*)(bbA + (s * 4 + ct) * 512);
            #pragma unroll
            for (int rt = 0; rt < 4; ++rt)
                #pragma unroll
                for (int ct = 0; ct < 4; ++ct)
                    accA[rt][ct] = __builtin_amdgcn_mfma_f32_16x16x32_bf16(
                        bfA[ct], af[rt], accA[rt][ct], 0, 0, 0);
        }
        STORE_ACCUM(accA, mc, m0)
    }
#undef ACCUM
#undef STORE_ACCUM
#undef INIT_ACC

    // un-rotate (o = (q+lg3)%3), reduce across the 4 lg groups, stash
    #pragma unroll
    for (int rt = 0; rt < 4; ++rt) {
        float q0 = racc[rt][0], q1 = racc[rt][1], q2 = racc[rt][2];
        float a0 = (lg3 == 0) ? q0 : ((lg3 == 1) ? q2 : q1);
        float a1 = (lg3 == 0) ? q1 : ((lg3 == 1) ? q0 : q2);
        float a2 = (lg3 == 0) ? q2 : ((lg3 == 1) ? q1 : q0);
        a0 += __shfl_xor(a0, 16, 64); a0 += __shfl_xor(a0, 32, 64);
        a1 += __shfl_xor(a1, 16, 64); a1 += __shfl_xor(a1, 32, 64);
        a2 += __shfl_xor(a2, 16, 64); a2 += __shfl_xor(a2, 32, 64);
        if (l < 16) {
            float* so = sOut + (wv * 64 + rt * 16 + lm) * 3;
            so[0] = a0; so[1] = a1; so[2] = a2;
        }
    }
    __syncthreads();
    if (tid < 192) {
        float s = sOut[tid] + sOut[192 + tid] + sOut[384 + tid] + sOut[576 + tid];
        int pix = tid / 3, o = tid - 3 * pix;
        dout[bb * 3 * HWp + o * HWp + I * 128 + J0 + pix] = s;
    }
}

extern "C" void kernel_launch(void* const* d_in, const int* in_sizes, int n_in,
                              void* d_out, int out_size, void* d_ws, size_t ws_size,
                              hipStream_t stream) {
    const float* x0      = (const float*)d_in[0];
    const float* feature = (const float*)d_in[1];
    const float* pos     = (const float*)d_in[2];
    const float* w1      = (const float*)d_in[4];
    const float* b1      = (const float*)d_in[5];
    const float* w2      = (const float*)d_in[6];
    const float* b2      = (const float*)d_in[7];
    const float* f2w1_w  = (const float*)d_in[8];
    const float* f2w1_b  = (const float*)d_in[9];
    const float* f2w2_w  = (const float*)d_in[10];
    const float* f2w2_b  = (const float*)d_in[11];

    float* out = (float*)d_out;
    float* ws  = (float*)d_ws;
    float* f1  = ws + F1_OFF;
    short* wB2 = (short*)(ws + WB2_OFF);
    short* wB1 = (short*)(ws + WB1_OFF);

    k13_conv1_cvt<<<945, THREADS, 0, stream>>>(feature, w1, b1, f1, f2w2_w, wB2,
                                               f2w1_w, wB1);
    k4_fused<<<Ntot / 64, THREADS, 0, stream>>>(f1, w2, b2, pos, wB1, f2w1_b,
                                                wB2, f2w2_b, x0, out);
}

// Round 16
// 106.221 us; speedup vs baseline: 1.0290x; 1.0290x over previous
//
#include <hip/hip_runtime.h>

#define THREADS 256

// problem sizes
#define Bsz 2
#define HWp 16384          // 128*128
#define Ntot (Bsz*HWp)     // 32768
#define HID 256
#define Mm 1728
#define FMC 17
#define W_OFF 98304        // 'out' elements precede 'weights' in d_out

// ws layout (in floats)
#define F1_OFF  0
#define F1_SZ   (Bsz*16*HWp)                 // 524288
#define WB2_OFF (F1_SZ + Ntot*FMC)           // bf16 B2 frags: 442368 shorts
#define WB1_OFF (WB2_OFF + (Mm*HID)/2)       // bf16 w1 frags: 8192 shorts

typedef __attribute__((ext_vector_type(8))) short bf16x8;
typedef __attribute__((ext_vector_type(4))) float f32x4;

static __device__ __forceinline__ short f2bf(float x) {
    unsigned u = __builtin_bit_cast(unsigned, x);
    unsigned r = (u + 0x7fff + ((u >> 16) & 1)) >> 16;
    return (short)r;
}
static __device__ __forceinline__ float bf2f(short s) {
    unsigned u = ((unsigned)(unsigned short)s) << 16;
    return __builtin_bit_cast(float, u);
}

// ---- K13: conv1 512 blocks (1 px/thread) + wB2 cvt 432 blocks + wB1 1 block
__global__ __launch_bounds__(THREADS) void k13_conv1_cvt(const float* __restrict__ feat,
                                                         const float* __restrict__ w1,
                                                         const float* __restrict__ b1,
                                                         float* __restrict__ f1,
                                                         const float* __restrict__ w2g,
                                                         short* __restrict__ wB2,
                                                         const float* __restrict__ w1g,
                                                         short* __restrict__ wB1) {
    int tid = threadIdx.x;
    if (blockIdx.x >= 944) {
        for (int idx = tid; idx < 8192; idx += THREADS) {
            int i = idx & 7, l = (idx >> 3) & 63, h = idx >> 9;
            int k = (l >> 4) * 8 + i, hid = h * 16 + (l & 15);
            wB1[idx] = (k < FMC) ? f2bf(w1g[hid * FMC + k]) : (short)0;
        }
        return;
    }
    if (blockIdx.x >= 512) {
        int t4 = ((blockIdx.x - 512) * THREADS + tid) * 4;
        int i = t4 & 7, l = (t4 >> 3) & 63, ct = (t4 >> 9) & 3, s = (t4 >> 11) & 7, mc = t4 >> 14;
        int col = mc * 64 + ct * 16 + (l & 15);
        int k0 = s * 32 + (l >> 4) * 8 + i;
        f32x4 w = *(const f32x4*)(w2g + col * HID + k0);
        short4 o;
        o.x = f2bf(w[0]); o.y = f2bf(w[1]); o.z = f2bf(w[2]); o.w = f2bf(w[3]);
        *(short4*)(wB2 + t4) = o;
        return;
    }
    // conv1: block = (bb, oc, 4 src rows); thread = one source pixel
    __shared__ float sW[4 * 64 * 4];   // [pp][ic][u*2+v] for this block's oc
    int b = blockIdx.x;
    int rg = b & 15, oc = (b >> 4) & 15, bb = b >> 8;
    int c = tid & 63, r = rg * 4 + (tid >> 6);

    #pragma unroll
    for (int q = 0; q < 4; ++q) {
        int e = tid * 4 + q;
        int v = e & 1, u = (e >> 1) & 1, ic = (e >> 2) & 63, pp = (e >> 8) & 3;
        int pi = pp >> 1, pj = pp & 1;
        float s = 0.f;
        for (int ki = 0; ki < 3; ++ki) {
            bool okki = pi ? (u ? (ki == 2) : (ki <= 1)) : (u ? (ki >= 1) : (ki == 0));
            if (!okki) continue;
            for (int kj = 0; kj < 3; ++kj) {
                bool okkj = pj ? (v ? (kj == 2) : (kj <= 1)) : (v ? (kj >= 1) : (kj == 0));
                if (okkj) s += w1[((oc * 64 + ic) * 3 + ki) * 3 + kj];
            }
        }
        sW[(pp * 64 + ic) * 4 + u * 2 + v] = s;
    }
    __syncthreads();

    float bias = b1[oc];
    float a00 = bias, a01 = bias, a10 = bias, a11 = bias;

    float mt = (r > 0) ? 1.f : 0.f, mb2 = (r < 63) ? 1.f : 0.f;
    float ml = (c > 0) ? 1.f : 0.f, mr2 = (c < 63) ? 1.f : 0.f;
    int ro0 = (r > 0) ? -64 : 0, ro2 = (r < 63) ? 64 : 0;
    int co0 = (c > 0) ? -1 : 0, co2 = (c < 63) ? 1 : 0;

    const float* fb = feat + bb * 64 * 4096 + r * 64 + c;
    for (int ic = 0; ic < 64; ++ic) {
        const float* p1 = fb + ic * 4096;
        const float* p0 = p1 + ro0;
        const float* p2 = p1 + ro2;
        float v00 = p0[co0] * (mt * ml), v01 = p0[0] * mt, v02 = p0[co2] * (mt * mr2);
        float v10 = p1[co0] * ml,        v11 = p1[0],      v12 = p1[co2] * mr2;
        float v20 = p2[co0] * (mb2 * ml), v21 = p2[0] * mb2, v22 = p2[co2] * (mb2 * mr2);

        f32x4 w0 = *(const f32x4*)(sW + (0 * 64 + ic) * 4);
        f32x4 w1v = *(const f32x4*)(sW + (1 * 64 + ic) * 4);
        f32x4 w2v = *(const f32x4*)(sW + (2 * 64 + ic) * 4);
        f32x4 w3 = *(const f32x4*)(sW + (3 * 64 + ic) * 4);

        a00 = fmaf(w0[0], v00, a00); a00 = fmaf(w0[1], v01, a00);
        a00 = fmaf(w0[2], v10, a00); a00 = fmaf(w0[3], v11, a00);
        a01 = fmaf(w1v[0], v01, a01); a01 = fmaf(w1v[1], v02, a01);
        a01 = fmaf(w1v[2], v11, a01); a01 = fmaf(w1v[3], v12, a01);
        a10 = fmaf(w2v[0], v10, a10); a10 = fmaf(w2v[1], v11, a10);
        a10 = fmaf(w2v[2], v20, a10); a10 = fmaf(w2v[3], v21, a10);
        a11 = fmaf(w3[0], v11, a11); a11 = fmaf(w3[1], v12, a11);
        a11 = fmaf(w3[2], v21, a11); a11 = fmaf(w3[3], v22, a11);
    }

    float* fo = f1 + (bb * 16 + oc) * HWp + (2 * r) * 128 + 2 * c;
    *reinterpret_cast<float2*>(fo)       = make_float2(fmaxf(a00, 0.f), fmaxf(a01, 0.f));
    *reinterpret_cast<float2*>(fo + 128) = make_float2(fmaxf(a10, 0.f), fmaxf(a11, 0.f));
}

// ---- K4: conv2 + GEMM1(MFMA) + GEMM2(MFMA) + fused einsum, one kernel -----
// Store path rebuilt: per-wave LDS staging (bf16, XOR-swizzled) then
// contiguous writeback — each store = 4 px x 256 B segments (vs 16 x 64 B).
__global__ __launch_bounds__(THREADS, 2) void k4_fused(const float* __restrict__ f1,
                                                       const float* __restrict__ w2,
                                                       const float* __restrict__ b2,
                                                       const float* __restrict__ pos,
                                                       const short* __restrict__ wB1,
                                                       const float* __restrict__ b1g,
                                                       const short* __restrict__ wB2,
                                                       const float* __restrict__ b2g,
                                                       const float* __restrict__ x0g,
                                                       float* __restrict__ dout) {
    __shared__ short sA[16384];       // 32 KB packed bf16 hdn
    __shared__ int   sOB[64];
    __shared__ float uni[3696];       // 14.8 KB phase-union (sF+sFM | sXT)
    __shared__ short sStage[16384];   // 32 KB: 4 waves x [64 px][64 units]

    short* sF  = (short*)uni;       // phase1: 3168 shorts  [ic*3+di][jc<66]
    float* sFM = uni + 1584;        // phase1: 2112 floats  [pix][33]
    short* sXT = (short*)uni;       // phase2: 6632 shorts  [jc][q], stride 195

    int tid = threadIdx.x;
    int n0 = blockIdx.x * 64;
    int bb = n0 >> 14, tt = n0 & 16383, I = tt >> 7, J0 = tt & 127;
    int i0 = I >> 1, jmin = J0 >> 1;

    // ---- phase 1a: stage f1 neighborhood (bf16) + zero sFM tail ----
    for (int e = tid; e < 3168; e += THREADS) {
        int jc = e % 66, r2 = e / 66;
        int di = r2 % 3, ic = r2 / 3;
        int y = I + di - 1, x = J0 + jc - 1;
        float v = 0.f;
        if ((unsigned)y < 128u && (unsigned)x < 128u)
            v = f1[(bb * 16 + ic) * HWp + y * 128 + x];
        sF[(ic * 3 + di) * 66 + jc] = f2bf(v);
    }
    for (int e = tid; e < 2112; e += THREADS) sFM[e] = 0.f;
    if (tid < 64) {
        int J = J0 + tid;
        int s = ((I & 1) << 1) | (J & 1);
        int p = ((I >> 1) << 6) | (J >> 1);
        sOB[tid] = W_OFF + ((bb * 4 + s) * 4096 + p) * Mm;
    }
    __syncthreads();

    // ---- phase 1b: conv2 -> sFM (thread = (pix, 4 oc)) ----
    {
        int pix = tid & 63, q = tid >> 6;
        float acc[4];
        #pragma unroll
        for (int o = 0; o < 4; ++o) acc[o] = b2[q * 4 + o];
        #pragma unroll 4
        for (int ic = 0; ic < 16; ++ic) {
            float v[9];
            #pragma unroll
            for (int di = 0; di < 3; ++di) {
                const short* row = sF + (ic * 3 + di) * 66 + pix;
                v[di * 3 + 0] = bf2f(row[0]);
                v[di * 3 + 1] = bf2f(row[1]);
                v[di * 3 + 2] = bf2f(row[2]);
            }
            #pragma unroll
            for (int o = 0; o < 4; ++o) {
                const float* w = w2 + ((q * 4 + o) * 16 + ic) * 9;  // wave-uniform
                acc[o] = fmaf(v[0], w[0], acc[o]); acc[o] = fmaf(v[1], w[1], acc[o]);
                acc[o] = fmaf(v[2], w[2], acc[o]); acc[o] = fmaf(v[3], w[3], acc[o]);
                acc[o] = fmaf(v[4], w[4], acc[o]); acc[o] = fmaf(v[5], w[5], acc[o]);
                acc[o] = fmaf(v[6], w[6], acc[o]); acc[o] = fmaf(v[7], w[7], acc[o]);
                acc[o] = fmaf(v[8], w[8], acc[o]);
            }
        }
        #pragma unroll
        for (int o = 0; o < 4; ++o) sFM[pix * 33 + q * 4 + o] = acc[o];
        if (q == 0) sFM[pix * 33 + 16] = pos[(I * 128 + J0 + pix) * 3];
    }
    __syncthreads();

    int wv = tid >> 6, l = tid & 63, lm = l & 15, lg = l >> 4;

    // ---- phase 1c: read fm row fragment for GEMM1 ----
    int row = wv * 16 + lm;
    bf16x8 af1;
    #pragma unroll
    for (int i = 0; i < 8; ++i) af1[i] = f2bf(sFM[row * 33 + lg * 8 + i]);
    __syncthreads();   // all sFM/sF reads done; uni is now free

    // ---- phase 1d: GEMM1 MFMA -> sA (packed), and stage sXT ----
    {
        const short* wb = wB1 + l * 8;
        int pbase = ((lg >> 1) * 64 + row) * 8 + (lg & 1) * 4;
        #pragma unroll 4
        for (int h = 0; h < 16; ++h) {
            bf16x8 bfr = *(const bf16x8*)(wb + h * 512);
            f32x4 bias = *(const f32x4*)(b1g + h * 16 + lg * 4);
            f32x4 acc = __builtin_amdgcn_mfma_f32_16x16x32_bf16(bfr, af1, bias, 0, 0, 0);
            unsigned c0 = (unsigned short)f2bf(fmaxf(acc[0], 0.f));
            unsigned c1 = (unsigned short)f2bf(fmaxf(acc[1], 0.f));
            unsigned c2 = (unsigned short)f2bf(fmaxf(acc[2], 0.f));
            unsigned c3 = (unsigned short)f2bf(fmaxf(acc[3], 0.f));
            uint2 uv; uv.x = c0 | (c1 << 16); uv.y = c2 | (c3 << 16);
            *(uint2*)(sA + pbase + h * 1024) = uv;
        }
    }
    {
        const float* x0b = x0g + bb * 64 * 4096;
        for (int e = tid; e < 6528; e += THREADS) {
            int ch = e / 102, r2 = e - ch * 102;
            int ki = r2 / 34, jc = r2 - ki * 34;
            int y = i0 + ki - 1, x = jmin + jc - 1;
            float v = 0.f;
            if ((unsigned)y < 64u && (unsigned)x < 64u) v = x0b[(ch * 64 + y) * 64 + x];
            sXT[jc * 195 + ch * 3 + ki] = f2bf(v);
        }
    }
    __syncthreads();

    // ---- phase 2: GEMM2 + staged contiguous store + fused einsum ----
    int lg3 = lg % 3, lg4 = lg * 4;
    int jl195[4];
    #pragma unroll
    for (int rt = 0; rt < 4; ++rt)
        jl195[rt] = (rt * 8 + (lm >> 1)) * 195;

    int sOBr[16];
    #pragma unroll
    for (int g = 0; g < 16; ++g) sOBr[g] = sOB[g * 4 + lg];

    const short* aptr = sA + lg * 512 + lm * 8;
    short* myStage = sStage + wv * 4096;

    float racc[4][3];
    #pragma unroll
    for (int rt = 0; rt < 4; ++rt) {
        racc[rt][0] = 0.f; racc[rt][1] = 0.f; racc[rt][2] = 0.f;
    }

#define ACCUM(QB)                                                              \
        _Pragma("unroll")                                                      \
        for (int ct = 0; ct < 4; ++ct) {                                       \
            int t = m0 + ct * 16 + lg4;                                        \
            int K0 = (t * 21846) >> 16;                                        \
            int rem3 = t - 3 * K0;                                             \
            int Q2 = (K0 * 21846) >> 16;                                       \
            int kja = K0 - 3 * Q2;                                             \
            int kqa = kja * 195 + Q2;                                          \
            int kqb = (kja == 2) ? (Q2 + 1) : (kqa + 195);                     \
            _Pragma("unroll")                                                  \
            for (int rt = 0; rt < 4; ++rt) {                                   \
                float xa = bf2f(sXT[jl195[rt] + kqa]);                         \
                float xb = bf2f(sXT[jl195[rt] + kqb]);                         \
                float x1 = (rem3 == 2) ? xb : xa;                              \
                float x2 = (rem3 >= 1) ? xb : xa;                              \
                racc[rt][(QB + ct) % 3] =                                      \
                    fmaf(acc[rt][ct][0], xa, racc[rt][(QB + ct) % 3]);         \
                racc[rt][(QB + ct + 1) % 3] =                                  \
                    fmaf(acc[rt][ct][1], x1, racc[rt][(QB + ct + 1) % 3]);     \
                racc[rt][(QB + ct + 2) % 3] =                                  \
                    fmaf(acc[rt][ct][2], x2, racc[rt][(QB + ct + 2) % 3]);     \
                racc[rt][(QB + ct) % 3] =                                      \
                    fmaf(acc[rt][ct][3], xb, racc[rt][(QB + ct) % 3]);         \
            }                                                                  \
        }

    // blocked contiguous chunk ranges per wave: {7,7,7,6}
    int lo = (wv < 3) ? wv * 7 : 21;
    int hi = (wv < 3) ? (lo + 7) : 27;
    for (int mc = lo; mc < hi; ++mc) {
        int m0 = mc * 64;
        f32x4 acc[4][4];
        #pragma unroll
        for (int ct = 0; ct < 4; ++ct) {
            f32x4 bias4 = *(const f32x4*)(b2g + m0 + ct * 16 + lg4);
            #pragma unroll
            for (int rt = 0; rt < 4; ++rt)
                acc[rt][ct] = bias4;
        }
        const short* bbase = wB2 + (size_t)mc * 16384 + l * 8;
        #pragma unroll 2
        for (int s = 0; s < 8; ++s) {
            bf16x8 af[4], bfr[4];
            #pragma unroll
            for (int rt = 0; rt < 4; ++rt)
                af[rt] = *(const bf16x8*)(aptr + s * 2048 + rt * 128);
            #pragma unroll
            for (int ct = 0; ct < 4; ++ct)
                bfr[ct] = *(const bf16x8*)(bbase + (s * 4 + ct) * 512);
            #pragma unroll
            for (int rt = 0; rt < 4; ++rt)
                #pragma unroll
                for (int ct = 0; ct < 4; ++ct)
                    acc[rt][ct] = __builtin_amdgcn_mfma_f32_16x16x32_bf16(
                        bfr[ct], af[rt], acc[rt][ct], 0, 0, 0);
        }
        // stage to LDS (bf16, XOR-swizzled units): px = rt*16+lm, unit = 4ct+lg
        #pragma unroll
        for (int rt = 0; rt < 4; ++rt) {
            int pxb = (rt * 16 + lm) * 64;
            #pragma unroll
            for (int ct = 0; ct < 4; ++ct) {
                int up = (((ct * 4 + lg) ^ lm) << 2);
                short4 sv;
                sv.x = f2bf(acc[rt][ct][0]); sv.y = f2bf(acc[rt][ct][1]);
                sv.z = f2bf(acc[rt][ct][2]); sv.w = f2bf(acc[rt][ct][3]);
                *(short4*)(myStage + pxb + up) = sv;
            }
        }
        // fused einsum from fp32 acc (unchanged)
        switch (mc % 3) {
            case 0: ACCUM(0); break;
            case 1: ACCUM(1); break;
            default: ACCUM(2); break;
        }
        // writeback: 16 stores, each 4 px x 256 B contiguous segments
        #pragma unroll
        for (int g = 0; g < 16; ++g) {
            int px = g * 4 + lg;
            int up = ((lm ^ (px & 15)) << 2);
            uint2 uv = *(const uint2*)(myStage + px * 64 + up);
            f32x4 v;
            v[0] = __builtin_bit_cast(float, uv.x << 16);
            v[1] = __builtin_bit_cast(float, uv.x & 0xffff0000u);
            v[2] = __builtin_bit_cast(float, uv.y << 16);
            v[3] = __builtin_bit_cast(float, uv.y & 0xffff0000u);
            *(f32x4*)(dout + sOBr[g] + m0 + lm * 4) = v;
        }
    }
#undef ACCUM

    __syncthreads();   // all writeback LDS reads done; sStage free for sOut
    float* sOut = (float*)sStage;

    // un-rotate (o = (q+lg3)%3), reduce across the 4 lg groups, stash
    #pragma unroll
    for (int rt = 0; rt < 4; ++rt) {
        float q0 = racc[rt][0], q1 = racc[rt][1], q2 = racc[rt][2];
        float a0 = (lg3 == 0) ? q0 : ((lg3 == 1) ? q2 : q1);
        float a1 = (lg3 == 0) ? q1 : ((lg3 == 1) ? q0 : q2);
        float a2 = (lg3 == 0) ? q2 : ((lg3 == 1) ? q1 : q0);
        a0 += __shfl_xor(a0, 16, 64); a0 += __shfl_xor(a0, 32, 64);
        a1 += __shfl_xor(a1, 16, 64); a1 += __shfl_xor(a1, 32, 64);
        a2 += __shfl_xor(a2, 16, 64); a2 += __shfl_xor(a2, 32, 64);
        if (l < 16) {
            float* so = sOut + (wv * 64 + rt * 16 + lm) * 3;
            so[0] = a0; so[1] = a1; so[2] = a2;
        }
    }
    __syncthreads();
    if (tid < 192) {
        float s = sOut[tid] + sOut[192 + tid] + sOut[384 + tid] + sOut[576 + tid];
        int pix = tid / 3, o = tid - 3 * pix;
        dout[bb * 3 * HWp + o * HWp + I * 128 + J0 + pix] = s;
    }
}

extern "C" void kernel_launch(void* const* d_in, const int* in_sizes, int n_in,
                              void* d_out, int out_size, void* d_ws, size_t ws_size,
                              hipStream_t stream) {
    const float* x0      = (const float*)d_in[0];
    const float* feature = (const float*)d_in[1];
    const float* pos     = (const float*)d_in[2];
    const float* w1      = (const float*)d_in[4];
    const float* b1      = (const float*)d_in[5];
    const float* w2      = (const float*)d_in[6];
    const float* b2      = (const float*)d_in[7];
    const float* f2w1_w  = (const float*)d_in[8];
    const float* f2w1_b  = (const float*)d_in[9];
    const float* f2w2_w  = (const float*)d_in[10];
    const float* f2w2_b  = (const float*)d_in[11];

    float* out = (float*)d_out;
    float* ws  = (float*)d_ws;
    float* f1  = ws + F1_OFF;
    short* wB2 = (short*)(ws + WB2_OFF);
    short* wB1 = (short*)(ws + WB1_OFF);

    k13_conv1_cvt<<<945, THREADS, 0, stream>>>(feature, w1, b1, f1, f2w2_w, wB2,
                                               f2w1_w, wB1);
    k4_fused<<<Ntot / 64, THREADS, 0, stream>>>(f1, w2, b2, pos, wB1, f2w1_b,
                                                wB2, f2w2_b, x0, out);
}